// Round 11
// baseline (15246.103 us; speedup 1.0000x reference)
//
#include <hip/hip_runtime.h>
#include <hip/hip_bf16.h>
#include <stdint.h>

// Problem sizes (fixed)
#define NB 512     // batch
#define NS 256     // source length
#define ND 256     // hidden dim
#define NT 256     // decode steps
#define NO 3       // output dim

#define LOG2E 1.44269504088896340736f
#define C2 (2.0f*LOG2E)

typedef float f32x2 __attribute__((ext_vector_type(2)));

#if __has_builtin(__builtin_amdgcn_exp2f)
__device__ __forceinline__ float exp2_fast(float x){ return __builtin_amdgcn_exp2f(x); }
#else
__device__ __forceinline__ float exp2_fast(float x){ return exp2f(x); }
#endif
#if __has_builtin(__builtin_amdgcn_rcpf)
__device__ __forceinline__ float rcp_fast(float x){ return __builtin_amdgcn_rcpf(x); }
#else
__device__ __forceinline__ float rcp_fast(float x){ return 1.0f/x; }
#endif

__device__ __forceinline__ float tanh_f(float x){
  float e = exp2_fast(x * C2);
  return 1.0f - 2.0f*rcp_fast(e + 1.0f);
}
__device__ __forceinline__ float sigm_f(float x){
  return rcp_fast(1.0f + exp2_fast(-x*LOG2E));
}
__device__ __forceinline__ float bflo(uint32_t u){ return __uint_as_float(u<<16); }
__device__ __forceinline__ float bfhi(uint32_t u){ return __uint_as_float(u & 0xffff0000u); }
__device__ __forceinline__ uint16_t f2bf(float f){   // round-to-nearest-even bf16
  uint32_t u = __float_as_uint(f);
  return (uint16_t)((u + 0x7fffu + ((u>>16)&1u)) >> 16);
}
__device__ __forceinline__ uint32_t pack2(float a, float b){
  return (uint32_t)f2bf(a) | ((uint32_t)f2bf(b) << 16);
}

// bf16-pair dot product: c + a.lo*b.lo + a.hi*b.hi
#if __has_builtin(__builtin_amdgcn_fdot2_f32_bf16)
typedef __bf16 bfp2 __attribute__((ext_vector_type(2)));
__device__ __forceinline__ float dot2bf(uint32_t a, uint32_t b, float c){
  return __builtin_amdgcn_fdot2_f32_bf16(__builtin_bit_cast(bfp2, a),
                                         __builtin_bit_cast(bfp2, b), c, false);
}
#else
__device__ __forceinline__ float dot2bf(uint32_t a, uint32_t b, float c){
  return c + bflo(a)*bflo(b) + bfhi(a)*bfhi(b);
}
#endif

// ---- fp8 e4m3 (OCP) encode/decode ----
__device__ __forceinline__ uint8_t enc_e4m3(float x){
  uint32_t sign = (__float_as_uint(x) >> 31) << 7;
  float y = fminf(fabsf(x), 448.0f);
  uint32_t u = __float_as_uint(y);
  int e = (int)(u >> 23) - 127;
  uint32_t code;
  if (e < -6){
    code = (uint32_t)__float2int_rn(y * 512.0f);      // denormal (ulp 2^-9)
  } else {
    uint32_t r = u + 0x000FFFFFu + ((u >> 20) & 1u);  // RNE to 3 mantissa bits
    e = (int)(r >> 23) - 127;
    code = (uint32_t)((e + 7) << 3) | ((r >> 20) & 7u);
    if (code > 0x7Eu) code = 0x7Eu;                   // max finite 448
  }
  return (uint8_t)(sign | code);
}

// HI must be a compile-time constant (builtin requires literal immediate).
#if __has_builtin(__builtin_amdgcn_cvt_pk_f32_fp8)
template<bool HI>
__device__ __forceinline__ f32x2 cvtpk_fp8(uint32_t w){
  return __builtin_amdgcn_cvt_pk_f32_fp8((int)w, HI);
}
#else
__device__ __forceinline__ float dec1_e4m3(uint32_t b){
  uint32_t s = (b >> 7) << 31;
  uint32_t em = b & 0x7fu;
  float mag;
  if (em >= 8u){
    mag = __uint_as_float((((em >> 3) + 120u) << 23) | ((em & 7u) << 20));
  } else {
    mag = (float)em * 0.001953125f;  // 2^-9
  }
  return __uint_as_float(s | __float_as_uint(mag));
}
template<bool HI>
__device__ __forceinline__ f32x2 cvtpk_fp8(uint32_t w){
  uint32_t p = HI ? (w >> 16) : (w & 0xffffu);
  f32x2 r; r.x = dec1_e4m3(p & 0xffu); r.y = dec1_e4m3(p >> 8); return r;
}
#endif

// S-phase: one dword = 4 consecutive e's. Temps die immediately (low VGPR).
__device__ __forceinline__ float s_dword(uint32_t dwv, float4 qq, float4 vv, float acc){
  f32x2 lo = cvtpk_fp8<false>(dwv);
  f32x2 hi = cvtpk_fp8<true>(dwv);
  float r;
  r = rcp_fast(exp2_fast(lo.x + qq.x) + 1.f); acc = fmaf(vv.x, r, acc);
  r = rcp_fast(exp2_fast(lo.y + qq.y) + 1.f); acc = fmaf(vv.y, r, acc);
  r = rcp_fast(exp2_fast(hi.x + qq.z) + 1.f); acc = fmaf(vv.z, r, acc);
  r = rcp_fast(exp2_fast(hi.y + qq.w) + 1.f); acc = fmaf(vv.w, r, acc);
  return acc;
}
// C-phase: one dword = 4 s-values of one dim, weighted by w4.
__device__ __forceinline__ float c_dword(uint32_t dwv, float4 w4, float acc){
  f32x2 lo = cvtpk_fp8<false>(dwv);
  f32x2 hi = cvtpk_fp8<true>(dwv);
  return fmaf(w4.x,lo.x, fmaf(w4.y,lo.y, fmaf(w4.z,hi.x, fmaf(w4.w,hi.y, acc))));
}

// ---------------- prep kernels ----------------

__global__ void k_transpose(const float* __restrict__ src, float* __restrict__ dst,
                            int R, int C){
  int idx = blockIdx.x*256 + threadIdx.x;
  if (idx < R*C){
    int r = idx / C, c = idx - r*C;
    dst[c*R + r] = src[idx];
  }
}

// UKQ[b][e16][s][16] fp8 e4m3, PRE-SCALED by 2*log2e: byte j of group = e (e16*16+j)
__global__ void __launch_bounds__(256) k_uk(const float* __restrict__ e_all,
    const float* __restrict__ UaT, const float* __restrict__ bu,
    uint8_t* __restrict__ UKQ){
  __shared__ float At[ND][20];
  const int t = threadIdx.x;
  const int m0 = blockIdx.x * 16;
  const int b  = m0 >> 8;
  const int s0 = m0 & (NS-1);
  #pragma unroll
  for (int i=0;i<16;i++)
    At[t][i] = e_all[(size_t)(m0+i)*ND + t];
  __syncthreads();
  float acc[16];
  float bue = bu[t];
  #pragma unroll
  for (int i=0;i<16;i++) acc[i] = bue;
  for (int d=0; d<ND; ++d){
    float u = UaT[d*ND + t];
    const float4 a0 = *(const float4*)&At[d][0];
    const float4 a1 = *(const float4*)&At[d][4];
    const float4 a2 = *(const float4*)&At[d][8];
    const float4 a3 = *(const float4*)&At[d][12];
    acc[0]+=a0.x*u;  acc[1]+=a0.y*u;  acc[2]+=a0.z*u;  acc[3]+=a0.w*u;
    acc[4]+=a1.x*u;  acc[5]+=a1.y*u;  acc[6]+=a1.z*u;  acc[7]+=a1.w*u;
    acc[8]+=a2.x*u;  acc[9]+=a2.y*u;  acc[10]+=a2.z*u; acc[11]+=a2.w*u;
    acc[12]+=a3.x*u; acc[13]+=a3.y*u; acc[14]+=a3.z*u; acc[15]+=a3.w*u;
  }
  const int e16 = t>>4, j = t&15;
  uint8_t* base = UKQ + (((size_t)b*16 + e16)*256 + s0)*16 + j;
  #pragma unroll
  for (int i=0;i<16;i++){
    uint32_t mine = enc_e4m3(acc[i] * C2);
    uint32_t other = (uint32_t)__shfl_xor((int)mine, 1);
    if (!(t & 1))
      *(uint16_t*)(base + (size_t)i*16) = (uint16_t)(mine | (other << 8));
  }
}

// EPQ[b][s4][d] u32 = fp8 {e[4s4+0][d], e[4s4+1][d], e[4s4+2][d], e[4s4+3][d]}
__global__ void k_epq(const float* __restrict__ e_all, uint32_t* __restrict__ EPQ){
  int idx = blockIdx.x*256 + threadIdx.x;
  if (idx >= NB*64*256) return;
  int d  = idx & 255;
  int s4 = (idx >> 8) & 63;
  int b  = idx >> 14;
  const float* e = e_all + ((size_t)b*NS + 4*s4)*ND + d;
  uint32_t v = (uint32_t)enc_e4m3(e[0])
             | ((uint32_t)enc_e4m3(e[ND])   << 8)
             | ((uint32_t)enc_e4m3(e[2*ND]) << 16)
             | ((uint32_t)enc_e4m3(e[3*ND]) << 24);
  EPQ[idx] = v;
}

// PKq[k2][g][d] u32 pairs over combined K-axis:
//   k2 in [0,130): x-part pairs {k=2k2, 2k2+1} of W_ih (k<259, else 0)
//   k2 in [130,258): h-part pairs of W_hh ; [258,260): zero pad
__global__ void k_pkq(const float* __restrict__ W_ih, const float* __restrict__ W_hh,
                      uint32_t* __restrict__ PKq){
  int idx = blockIdx.x*256 + threadIdx.x;   // ((k2*3)+g)*256 + d
  if (idx >= 260*3*256) return;
  int d  = idx & 255;
  int gk = idx >> 8;
  int k2 = gk/3, g = gk - 3*k2;
  int col = g*256 + d;
  float w0 = 0.f, w1 = 0.f;
  if (k2 < 130){
    int k0 = 2*k2, k1 = k0+1;
    w0 = W_ih[(size_t)col*259 + k0];
    w1 = (k1 < 259) ? W_ih[(size_t)col*259 + k1] : 0.f;
  } else if (k2 < 258){
    int kk = 2*(k2-130);
    w0 = W_hh[(size_t)col*256 + kk];
    w1 = W_hh[(size_t)col*256 + kk+1];
  }
  PKq[idx] = pack2(w0, w1);
}

// PQ[k2][d] = {bf16 Wa[d][2k2], bf16 Wa[d][2k2+1]}
__global__ void k_pack_q(const float* __restrict__ Wa, uint32_t* __restrict__ PQ){
  int idx = blockIdx.x*256 + threadIdx.x;   // k2*256 + d
  if (idx >= 128*256) return;
  int d = idx & 255, k2 = idx >> 8;
  PQ[idx] = pack2(Wa[(size_t)d*256 + 2*k2], Wa[(size_t)d*256 + 2*k2 + 1]);
}

// ---------------- persistent decode kernel ----------------
// 256 blocks x 1024 threads; TWO batch elements per block (weight reuse x2).
// R4 skeleton; S and C stream fp8 (half the bytes) with 4-deep load batches
// to stay under the 64-VGPR ceiling (no spill).
// t: d = t&255, q4 = t>>8, bi = q4>>1 (batch-in-block), half = q4&1.
__global__ void __launch_bounds__(1024, 4) k_decode(
    const uint8_t* __restrict__ UKQ, const uint32_t* __restrict__ EPQ,
    const uint32_t* __restrict__ PKq, const uint32_t* __restrict__ PQ,
    const float* __restrict__ e_last,
    const float* __restrict__ Va, const float* __restrict__ bv,
    const float* __restrict__ b_ih, const float* __restrict__ b_hh,
    const float* __restrict__ ba, const float* __restrict__ bo,
    const float* __restrict__ Wo,
    float* __restrict__ dout, float* __restrict__ hT_out, float* __restrict__ ca)
{
  __shared__ float    hf[2][ND];
  __shared__ float    xin[2][4];
  __shared__ uint32_t xb[2][260];           // bf16 pairs: [0..129]=ctx+x, [130..257]=h, pad
  __shared__ __align__(16) float qL[2][ND]; // pre-scaled q per batch
  __shared__ __align__(16) float va2[ND];   // 2*Va
  __shared__ float    WoL[3*ND];
  __shared__ float    qpart[2][2][ND];
  __shared__ float    spart[2][2][ND];
  __shared__ __align__(16) float cpart[2][8][ND];
  __shared__ float    gpart[2][4][3][ND];
  __shared__ __align__(16) float wl[2][NS]; // softmax weights (f32)
  __shared__ float    red[16];

  const int t    = threadIdx.x;
  const int d    = t & 255;
  const int q4   = t >> 8;
  const int bi   = q4 >> 1;
  const int half = q4 & 1;
  const int lane = t & 63;
  const int w    = t >> 6;
  const int b0   = blockIdx.x * 2;

  // ---- init ----
  if (q4 == 0){
    hf[0][d] = e_last[(size_t)b0*ND + d];
    va2[d]   = 2.0f*Va[d];
    WoL[d] = Wo[d]; WoL[256+d] = Wo[256+d]; WoL[512+d] = Wo[512+d];
    if (d < 4){ xin[0][d]=0.f; xin[1][d]=0.f; }
  } else if (q4 == 1){
    hf[1][d] = e_last[(size_t)(b0+1)*ND + d];
  }
  const float bias_r  = b_ih[d]     + b_hh[d];
  const float bias_z  = b_ih[256+d] + b_hh[256+d];
  const float bias_ni = b_ih[512+d];
  const float bias_nh = b_hh[512+d];
  const float ba_d = ba[d];
  const float bv0  = bv[0];
  const float bo0 = bo[0], bo1 = bo[1], bo2 = bo[2];
  __syncthreads();
  if (t < 256){
    int bb = t>>7, i = t&127;
    xb[bb][130+i] = pack2(hf[bb][2*i], hf[bb][2*i+1]);
  }
  if (t == 256){
    xb[0][128]=0u; xb[0][129]=0u; xb[0][258]=0u; xb[0][259]=0u;
    xb[1][128]=0u; xb[1][129]=0u; xb[1][258]=0u; xb[1][259]=0u;
  }
  float sumVaH = 0.f;
  {
    #pragma unroll 8
    for (int e = half*128; e < half*128+128; ++e) sumVaH += va2[e];
    sumVaH *= 0.5f;
  }
  __syncthreads();

  // S-phase base: batch bi, s=d, e16-groups [half*8, half*8+8)
  const uint8_t*  ukq  = UKQ + (((size_t)(b0+bi)*16 + half*8)*256 + d)*16;
  const uint32_t* epqw = EPQ + (size_t)(b0+(w>>3))*64*256;   // C-phase batch = w>>3
  float* ca_bq = ca + (size_t)(b0 + (q4&1))*(NT*NS);         // used when q4<2

  #pragma unroll 1
  for (int step=0; step<NT; ++step){
    // ---- Q: q = h @ Wa^T + ba ; split (batch bi) x (k-half) ----
    {
      float aq = 0.f;
      const uint32_t* pq = PQ + (size_t)(half*64)*256 + d;
      const uint32_t* xh = &xb[bi][130 + half*64];
      #pragma unroll 1
      for (int kk=0; kk<64; kk+=8){
        uint32_t wv[8], xv[8];
        #pragma unroll
        for (int j=0;j<8;j++){ wv[j] = pq[(kk+j)*256]; xv[j] = xh[kk+j]; }
        #pragma unroll
        for (int j=0;j<8;j++) aq = dot2bf(wv[j], xv[j], aq);
      }
      qpart[bi][half][d] = aq;
    }
    __syncthreads();
    if (q4 < 2)
      qL[q4][d] = (qpart[q4][0][d] + qpart[q4][1][d] + ba_d) * C2;
    __syncthreads();

    // ---- S: scores (batch bi, s=d, e-half); fp8, 4-deep batches ----
    {
      float acc = 0.f;
      #pragma unroll
      for (int gq=0; gq<2; ++gq){
        uint4 u0 = *(const uint4*)(ukq + (size_t)(gq*4+0)*4096);
        uint4 u1 = *(const uint4*)(ukq + (size_t)(gq*4+1)*4096);
        uint4 u2 = *(const uint4*)(ukq + (size_t)(gq*4+2)*4096);
        uint4 u3 = *(const uint4*)(ukq + (size_t)(gq*4+3)*4096);
        const float* qb = &qL[bi][half*128 + gq*64];
        const float* vb = &va2[half*128 + gq*64];
        acc = s_dword(u0.x, *(const float4*)&qb[0],  *(const float4*)&vb[0],  acc);
        acc = s_dword(u0.y, *(const float4*)&qb[4],  *(const float4*)&vb[4],  acc);
        acc = s_dword(u0.z, *(const float4*)&qb[8],  *(const float4*)&vb[8],  acc);
        acc = s_dword(u0.w, *(const float4*)&qb[12], *(const float4*)&vb[12], acc);
        acc = s_dword(u1.x, *(const float4*)&qb[16], *(const float4*)&vb[16], acc);
        acc = s_dword(u1.y, *(const float4*)&qb[20], *(const float4*)&vb[20], acc);
        acc = s_dword(u1.z, *(const float4*)&qb[24], *(const float4*)&vb[24], acc);
        acc = s_dword(u1.w, *(const float4*)&qb[28], *(const float4*)&vb[28], acc);
        acc = s_dword(u2.x, *(const float4*)&qb[32], *(const float4*)&vb[32], acc);
        acc = s_dword(u2.y, *(const float4*)&qb[36], *(const float4*)&vb[36], acc);
        acc = s_dword(u2.z, *(const float4*)&qb[40], *(const float4*)&vb[40], acc);
        acc = s_dword(u2.w, *(const float4*)&qb[44], *(const float4*)&vb[44], acc);
        acc = s_dword(u3.x, *(const float4*)&qb[48], *(const float4*)&vb[48], acc);
        acc = s_dword(u3.y, *(const float4*)&qb[52], *(const float4*)&vb[52], acc);
        acc = s_dword(u3.z, *(const float4*)&qb[56], *(const float4*)&vb[56], acc);
        acc = s_dword(u3.w, *(const float4*)&qb[60], *(const float4*)&vb[60], acc);
      }
      spart[bi][half][d] = sumVaH - acc;
    }
    __syncthreads();

    // ---- softmax (no max-subtract; |score| <= sum|Va|+|bv| is small) ----
    float p_reg = 0.f;
    if (q4 < 2){
      float sc = spart[q4][0][d] + spart[q4][1][d] + bv0;
      p_reg = exp2_fast(sc * LOG2E);
      float ssum = p_reg;
      #pragma unroll
      for (int o=32;o;o>>=1) ssum += __shfl_xor(ssum, o);
      if (lane==0) red[w] = ssum;      // waves 0-3 (batch0), 4-7 (batch1)
    }
    __syncthreads();
    if (q4 < 2){
      const int rb = q4*4;
      float ssum = (red[rb]+red[rb+1]) + (red[rb+2]+red[rb+3]);
      float wgt = p_reg * rcp_fast(ssum);
      __builtin_nontemporal_store(wgt, &ca_bq[(size_t)step*NS + d]);
      wl[q4][d] = wgt;
    }
    __syncthreads();

    // ---- C: ctx ; wave w -> (batch w>>3, s4-range (w&7)*8..+8); fp8, 4-deep ----
    {
      const int cb = w>>3, sub = w&7;
      float c0=0,c1=0,c2=0,c3=0;
      #pragma unroll
      for (int gq=0; gq<2; ++gq){
        const int s40 = sub*8 + gq*4;
        uint4 e0v = *(const uint4*)(epqw + (size_t)(s40+0)*256 + lane*4);
        uint4 e1v = *(const uint4*)(epqw + (size_t)(s40+1)*256 + lane*4);
        uint4 e2v = *(const uint4*)(epqw + (size_t)(s40+2)*256 + lane*4);
        uint4 e3v = *(const uint4*)(epqw + (size_t)(s40+3)*256 + lane*4);
        float4 w40 = *(const float4*)&wl[cb][(s40+0)*4];
        c0=c_dword(e0v.x,w40,c0); c1=c_dword(e0v.y,w40,c1);
        c2=c_dword(e0v.z,w40,c2); c3=c_dword(e0v.w,w40,c3);
        float4 w41 = *(const float4*)&wl[cb][(s40+1)*4];
        c0=c_dword(e1v.x,w41,c0); c1=c_dword(e1v.y,w41,c1);
        c2=c_dword(e1v.z,w41,c2); c3=c_dword(e1v.w,w41,c3);
        float4 w42 = *(const float4*)&wl[cb][(s40+2)*4];
        c0=c_dword(e2v.x,w42,c0); c1=c_dword(e2v.y,w42,c1);
        c2=c_dword(e2v.z,w42,c2); c3=c_dword(e2v.w,w42,c3);
        float4 w43 = *(const float4*)&wl[cb][(s40+3)*4];
        c0=c_dword(e3v.x,w43,c0); c1=c_dword(e3v.y,w43,c1);
        c2=c_dword(e3v.z,w43,c2); c3=c_dword(e3v.w,w43,c3);
      }
      *(float4*)&cpart[cb][sub][lane*4] = make_float4(c0,c1,c2,c3);
    }
    __syncthreads();
    if (q4 < 2){
      float cx = 0.f;
      #pragma unroll
      for (int i=0;i<8;i++) cx += cpart[q4][i][d];
      float other = __shfl_xor(cx, 1);
      if (!(d&1)) xb[q4][d>>1] = pack2(cx, other);
      if (d==128) xb[q4][128] = pack2(xin[q4][0], xin[q4][1]);
      if (d==129) xb[q4][129] = pack2(xin[q4][2], 0.f);
    }
    __syncthreads();

    // ---- G: gates ; quarter q4 = k2-quarter, BOTH batches per weight load ----
    {
      float a0r=0,a0z=0,a0n=0, a1r=0,a1z=0,a1n=0;
      const int k0 = q4*65;
      const uint32_t* pk = PKq + (size_t)k0*768 + d;
      #pragma unroll 1
      for (int g=0; g<64; g+=8){
        uint32_t wr[8], wz[8], wn[8], x0[8], x1[8];
        #pragma unroll
        for (int j=0;j<8;j++){
          const uint32_t* p = pk + (size_t)(g+j)*768;
          wr[j]=p[0]; wz[j]=p[256]; wn[j]=p[512];
          x0[j]=xb[0][k0+g+j]; x1[j]=xb[1][k0+g+j];
        }
        #pragma unroll
        for (int j=0;j<8;j++){
          a0r=dot2bf(wr[j],x0[j],a0r); a0z=dot2bf(wz[j],x0[j],a0z); a0n=dot2bf(wn[j],x0[j],a0n);
          a1r=dot2bf(wr[j],x1[j],a1r); a1z=dot2bf(wz[j],x1[j],a1z); a1n=dot2bf(wn[j],x1[j],a1n);
        }
      }
      { // last k2 (65th)
        const uint32_t* p = pk + (size_t)64*768;
        uint32_t w0=p[0], w1=p[256], w2=p[512];
        uint32_t xa=xb[0][k0+64], xc=xb[1][k0+64];
        a0r=dot2bf(w0,xa,a0r); a0z=dot2bf(w1,xa,a0z); a0n=dot2bf(w2,xa,a0n);
        a1r=dot2bf(w0,xc,a1r); a1z=dot2bf(w1,xc,a1z); a1n=dot2bf(w2,xc,a1n);
      }
      gpart[0][q4][0][d]=a0r; gpart[0][q4][1][d]=a0z; gpart[0][q4][2][d]=a0n;
      gpart[1][q4][0][d]=a1r; gpart[1][q4][1][d]=a1z; gpart[1][q4][2][d]=a1n;
    }
    __syncthreads();
    if (q4 < 2){
      float ar  = (gpart[q4][0][0][d]+gpart[q4][1][0][d]) + (gpart[q4][2][0][d]+gpart[q4][3][0][d]) + bias_r;
      float az  = (gpart[q4][0][1][d]+gpart[q4][1][1][d]) + (gpart[q4][2][1][d]+gpart[q4][3][1][d]) + bias_z;
      float ani =  gpart[q4][0][2][d]+gpart[q4][1][2][d] + bias_ni;   // x-part (k2<130)
      float anh =  gpart[q4][2][2][d]+gpart[q4][3][2][d] + bias_nh;   // h-part
      float rg = sigm_f(ar);
      float zg = sigm_f(az);
      float ng = tanh_f(ani + rg*anh);
      float hnew = (1.f-zg)*ng + zg*hf[q4][d];
      hf[q4][d] = hnew;
      float other = __shfl_xor(hnew, 1);
      if (!(d&1)) xb[q4][130 + (d>>1)] = pack2(hnew, other);
    }
    __syncthreads();

    // ---- out projection: waves 0 (batch0) and 8 (batch1) ----
    if ((w & 7) == 0){
      const int bq = w >> 3;
      float p0=0,p1=0,p2=0;
      #pragma unroll
      for (int i=0;i<4;i++){
        float hv = hf[bq][i*64 + lane];
        p0 = fmaf(hv, WoL[      i*64+lane], p0);
        p1 = fmaf(hv, WoL[256 + i*64+lane], p1);
        p2 = fmaf(hv, WoL[512 + i*64+lane], p2);
      }
      #pragma unroll
      for (int o=32;o;o>>=1){
        p0+=__shfl_xor(p0,o); p1+=__shfl_xor(p1,o); p2+=__shfl_xor(p2,o);
      }
      if (lane==0){
        float o0=p0+bo0, o1=p1+bo1, o2=p2+bo2;
        float* do_b = dout + (size_t)(b0+bq)*(NT*NO);
        __builtin_nontemporal_store(o0, &do_b[(size_t)step*NO+0]);
        __builtin_nontemporal_store(o1, &do_b[(size_t)step*NO+1]);
        __builtin_nontemporal_store(o2, &do_b[(size_t)step*NO+2]);
        xin[bq][0]=o0; xin[bq][1]=o1; xin[bq][2]=o2;
      }
    }
    // next step's barriers order xin/hf consumers
  }

  __syncthreads();
  if (q4 < 2) hT_out[(size_t)(b0+q4)*ND + d] = hf[q4][d];
}

// ---------------- host launch ----------------

extern "C" void kernel_launch(void* const* d_in, const int* in_sizes, int n_in,
                              void* d_out, int out_size, void* d_ws, size_t ws_size,
                              hipStream_t stream) {
  const float* e_all  = (const float*)d_in[0];
  const float* e_last = (const float*)d_in[1];
  const float* Wa     = (const float*)d_in[2];
  const float* ba     = (const float*)d_in[3];
  const float* Ua     = (const float*)d_in[4];
  const float* bu     = (const float*)d_in[5];
  const float* Va     = (const float*)d_in[6];
  const float* bv     = (const float*)d_in[7];
  const float* W_ih   = (const float*)d_in[8];
  const float* b_ih   = (const float*)d_in[9];
  const float* W_hh   = (const float*)d_in[10];
  const float* b_hh   = (const float*)d_in[11];
  const float* Wo     = (const float*)d_in[12];
  const float* bo     = (const float*)d_in[13];

  // workspace layout (~68.3 MB)
  char* ws = (char*)d_ws;
  uint8_t*  UKQ = (uint8_t*) (ws + 0ull);            // fp8 [B][16][S][16]    33554432 B
  uint32_t* EPQ = (uint32_t*)(ws + 33554432ull);     // u32 [B][64][256]      33554432 B
  uint32_t* PKq = (uint32_t*)(ws + 67108864ull);     // u32 [260][3][256]       798720 B
  uint32_t* PQ  = (uint32_t*)(ws + 67907584ull);     // u32 [128][256]          131072 B
  float*    UaT = (float*)   (ws + 68038656ull);     // f32 [256][256]          262144 B

  float* dout = (float*)d_out;                       // [B][T][3]
  float* hT   = dout + (size_t)NB*NT*NO;             // [B][D]
  float* ca   = hT   + (size_t)NB*ND;                // [B][T*S]

  // prep
  k_transpose<<<(ND*ND+255)/256,256,0,stream>>>(Ua, UaT, ND, ND);
  k_uk<<<NB*NS/16,256,0,stream>>>(e_all, UaT, bu, UKQ);
  k_epq<<<(NB*64*256+255)/256,256,0,stream>>>(e_all, EPQ);
  k_pkq<<<(260*3*256+255)/256,256,0,stream>>>(W_ih, W_hh, PKq);
  k_pack_q<<<(128*256+255)/256,256,0,stream>>>(Wa, PQ);

  // persistent decode: 256 blocks x 1024 threads, 2 batch elements per block
  k_decode<<<NB/2,1024,0,stream>>>(UKQ, EPQ, PKq, PQ, e_last, Va, bv,
                                   b_ih, b_hh, ba, bo, Wo, dout, hT, ca);
}

// Round 12
// 6858.034 us; speedup vs baseline: 2.2231x; 2.2231x over previous
//
#include <hip/hip_runtime.h>
#include <hip/hip_bf16.h>
#include <stdint.h>

// Problem sizes (fixed)
#define NB 512     // batch
#define NS 256     // source length
#define ND 256     // hidden dim
#define NT 256     // decode steps
#define NO 3       // output dim

#define LOG2E 1.44269504088896340736f
#define C2 (2.0f*LOG2E)

typedef float f32x2 __attribute__((ext_vector_type(2)));

#if __has_builtin(__builtin_amdgcn_exp2f)
__device__ __forceinline__ float exp2_fast(float x){ return __builtin_amdgcn_exp2f(x); }
#else
__device__ __forceinline__ float exp2_fast(float x){ return exp2f(x); }
#endif
#if __has_builtin(__builtin_amdgcn_rcpf)
__device__ __forceinline__ float rcp_fast(float x){ return __builtin_amdgcn_rcpf(x); }
#else
__device__ __forceinline__ float rcp_fast(float x){ return 1.0f/x; }
#endif

__device__ __forceinline__ float tanh_f(float x){
  float e = exp2_fast(x * C2);
  return 1.0f - 2.0f*rcp_fast(e + 1.0f);
}
__device__ __forceinline__ float sigm_f(float x){
  return rcp_fast(1.0f + exp2_fast(-x*LOG2E));
}
__device__ __forceinline__ float bflo(uint32_t u){ return __uint_as_float(u<<16); }
__device__ __forceinline__ float bfhi(uint32_t u){ return __uint_as_float(u & 0xffff0000u); }
__device__ __forceinline__ uint16_t f2bf(float f){   // round-to-nearest-even bf16
  uint32_t u = __float_as_uint(f);
  return (uint16_t)((u + 0x7fffu + ((u>>16)&1u)) >> 16);
}
__device__ __forceinline__ uint32_t pack2(float a, float b){
  return (uint32_t)f2bf(a) | ((uint32_t)f2bf(b) << 16);
}

// bf16-pair dot product: c + a.lo*b.lo + a.hi*b.hi
#if __has_builtin(__builtin_amdgcn_fdot2_f32_bf16)
typedef __bf16 bfp2 __attribute__((ext_vector_type(2)));
__device__ __forceinline__ float dot2bf(uint32_t a, uint32_t b, float c){
  return __builtin_amdgcn_fdot2_f32_bf16(__builtin_bit_cast(bfp2, a),
                                         __builtin_bit_cast(bfp2, b), c, false);
}
#else
__device__ __forceinline__ float dot2bf(uint32_t a, uint32_t b, float c){
  return c + bflo(a)*bflo(b) + bfhi(a)*bfhi(b);
}
#endif

// ---- fp8 e4m3 (OCP) encode/decode ----
__device__ __forceinline__ uint8_t enc_e4m3(float x){
  uint32_t sign = (__float_as_uint(x) >> 31) << 7;
  float y = fminf(fabsf(x), 448.0f);
  uint32_t u = __float_as_uint(y);
  int e = (int)(u >> 23) - 127;
  uint32_t code;
  if (e < -6){
    code = (uint32_t)__float2int_rn(y * 512.0f);      // denormal (ulp 2^-9)
  } else {
    uint32_t r = u + 0x000FFFFFu + ((u >> 20) & 1u);  // RNE to 3 mantissa bits
    e = (int)(r >> 23) - 127;
    code = (uint32_t)((e + 7) << 3) | ((r >> 20) & 7u);
    if (code > 0x7Eu) code = 0x7Eu;                   // max finite 448
  }
  return (uint8_t)(sign | code);
}

// HI must be a compile-time constant (builtin requires literal immediate).
#if __has_builtin(__builtin_amdgcn_cvt_pk_f32_fp8)
template<bool HI>
__device__ __forceinline__ f32x2 cvtpk_fp8(uint32_t w){
  return __builtin_amdgcn_cvt_pk_f32_fp8((int)w, HI);
}
#else
__device__ __forceinline__ float dec1_e4m3(uint32_t b){
  uint32_t s = (b >> 7) << 31;
  uint32_t em = b & 0x7fu;
  float mag;
  if (em >= 8u){
    mag = __uint_as_float((((em >> 3) + 120u) << 23) | ((em & 7u) << 20));
  } else {
    mag = (float)em * 0.001953125f;  // 2^-9
  }
  return __uint_as_float(s | __float_as_uint(mag));
}
template<bool HI>
__device__ __forceinline__ f32x2 cvtpk_fp8(uint32_t w){
  uint32_t p = HI ? (w >> 16) : (w & 0xffffu);
  f32x2 r; r.x = dec1_e4m3(p & 0xffu); r.y = dec1_e4m3(p >> 8); return r;
}
#endif

// S-phase: one dword = 4 consecutive e's. Temps die immediately (low VGPR).
__device__ __forceinline__ float s_dword(uint32_t dwv, float4 qq, float4 vv, float acc){
  f32x2 lo = cvtpk_fp8<false>(dwv);
  f32x2 hi = cvtpk_fp8<true>(dwv);
  float r;
  r = rcp_fast(exp2_fast(lo.x + qq.x) + 1.f); acc = fmaf(vv.x, r, acc);
  r = rcp_fast(exp2_fast(lo.y + qq.y) + 1.f); acc = fmaf(vv.y, r, acc);
  r = rcp_fast(exp2_fast(hi.x + qq.z) + 1.f); acc = fmaf(vv.z, r, acc);
  r = rcp_fast(exp2_fast(hi.y + qq.w) + 1.f); acc = fmaf(vv.w, r, acc);
  return acc;
}
// C-phase: one dword = 4 s-values of one dim, weighted by w4.
__device__ __forceinline__ float c_dword(uint32_t dwv, float4 w4, float acc){
  f32x2 lo = cvtpk_fp8<false>(dwv);
  f32x2 hi = cvtpk_fp8<true>(dwv);
  return fmaf(w4.x,lo.x, fmaf(w4.y,lo.y, fmaf(w4.z,hi.x, fmaf(w4.w,hi.y, acc))));
}

// ---------------- prep kernels ----------------

__global__ void k_transpose(const float* __restrict__ src, float* __restrict__ dst,
                            int R, int C){
  int idx = blockIdx.x*256 + threadIdx.x;
  if (idx < R*C){
    int r = idx / C, c = idx - r*C;
    dst[c*R + r] = src[idx];
  }
}

// UKQ[b][e16][s][16] fp8 e4m3, PRE-SCALED by 2*log2e: byte j of group = e (e16*16+j)
__global__ void __launch_bounds__(256) k_uk(const float* __restrict__ e_all,
    const float* __restrict__ UaT, const float* __restrict__ bu,
    uint8_t* __restrict__ UKQ){
  __shared__ float At[ND][20];
  const int t = threadIdx.x;
  const int m0 = blockIdx.x * 16;
  const int b  = m0 >> 8;
  const int s0 = m0 & (NS-1);
  #pragma unroll
  for (int i=0;i<16;i++)
    At[t][i] = e_all[(size_t)(m0+i)*ND + t];
  __syncthreads();
  float acc[16];
  float bue = bu[t];
  #pragma unroll
  for (int i=0;i<16;i++) acc[i] = bue;
  for (int d=0; d<ND; ++d){
    float u = UaT[d*ND + t];
    const float4 a0 = *(const float4*)&At[d][0];
    const float4 a1 = *(const float4*)&At[d][4];
    const float4 a2 = *(const float4*)&At[d][8];
    const float4 a3 = *(const float4*)&At[d][12];
    acc[0]+=a0.x*u;  acc[1]+=a0.y*u;  acc[2]+=a0.z*u;  acc[3]+=a0.w*u;
    acc[4]+=a1.x*u;  acc[5]+=a1.y*u;  acc[6]+=a1.z*u;  acc[7]+=a1.w*u;
    acc[8]+=a2.x*u;  acc[9]+=a2.y*u;  acc[10]+=a2.z*u; acc[11]+=a2.w*u;
    acc[12]+=a3.x*u; acc[13]+=a3.y*u; acc[14]+=a3.z*u; acc[15]+=a3.w*u;
  }
  const int e16 = t>>4, j = t&15;
  uint8_t* base = UKQ + (((size_t)b*16 + e16)*256 + s0)*16 + j;
  #pragma unroll
  for (int i=0;i<16;i++){
    uint32_t mine = enc_e4m3(acc[i] * C2);
    uint32_t other = (uint32_t)__shfl_xor((int)mine, 1);
    if (!(t & 1))
      *(uint16_t*)(base + (size_t)i*16) = (uint16_t)(mine | (other << 8));
  }
}

// EPQ[b][s4][d] u32 = fp8 {e[4s4+0][d], e[4s4+1][d], e[4s4+2][d], e[4s4+3][d]}
__global__ void k_epq(const float* __restrict__ e_all, uint32_t* __restrict__ EPQ){
  int idx = blockIdx.x*256 + threadIdx.x;
  if (idx >= NB*64*256) return;
  int d  = idx & 255;
  int s4 = (idx >> 8) & 63;
  int b  = idx >> 14;
  const float* e = e_all + ((size_t)b*NS + 4*s4)*ND + d;
  uint32_t v = (uint32_t)enc_e4m3(e[0])
             | ((uint32_t)enc_e4m3(e[ND])   << 8)
             | ((uint32_t)enc_e4m3(e[2*ND]) << 16)
             | ((uint32_t)enc_e4m3(e[3*ND]) << 24);
  EPQ[idx] = v;
}

// PKq[k2][g][d] u32 pairs over combined K-axis:
//   k2 in [0,130): x-part pairs {k=2k2, 2k2+1} of W_ih (k<259, else 0)
//   k2 in [130,258): h-part pairs of W_hh ; [258,260): zero pad
__global__ void k_pkq(const float* __restrict__ W_ih, const float* __restrict__ W_hh,
                      uint32_t* __restrict__ PKq){
  int idx = blockIdx.x*256 + threadIdx.x;   // ((k2*3)+g)*256 + d
  if (idx >= 260*3*256) return;
  int d  = idx & 255;
  int gk = idx >> 8;
  int k2 = gk/3, g = gk - 3*k2;
  int col = g*256 + d;
  float w0 = 0.f, w1 = 0.f;
  if (k2 < 130){
    int k0 = 2*k2, k1 = k0+1;
    w0 = W_ih[(size_t)col*259 + k0];
    w1 = (k1 < 259) ? W_ih[(size_t)col*259 + k1] : 0.f;
  } else if (k2 < 258){
    int kk = 2*(k2-130);
    w0 = W_hh[(size_t)col*256 + kk];
    w1 = W_hh[(size_t)col*256 + kk+1];
  }
  PKq[idx] = pack2(w0, w1);
}

// PQ[k2][d] = {bf16 Wa[d][2k2], bf16 Wa[d][2k2+1]}
__global__ void k_pack_q(const float* __restrict__ Wa, uint32_t* __restrict__ PQ){
  int idx = blockIdx.x*256 + threadIdx.x;   // k2*256 + d
  if (idx >= 128*256) return;
  int d = idx & 255, k2 = idx >> 8;
  PQ[idx] = pack2(Wa[(size_t)d*256 + 2*k2], Wa[(size_t)d*256 + 2*k2 + 1]);
}

// ---------------- persistent decode kernel ----------------
// 256 blocks x 1024 threads; each block processes its TWO batches SEQUENTIALLY
// (2 rounds x 256 steps). Per round, that batch's fp8 UK (64KB) + EP (64KB)
// live in LDS -> steady-state global traffic = L2-resident weights only.
// t: d = t&255, q4 = t>>8 (quarter), lane = t&63, w = t>>6 (0..15).
__global__ void __launch_bounds__(1024, 4) k_decode(
    const uint8_t* __restrict__ UKQ, const uint32_t* __restrict__ EPQ,
    const uint32_t* __restrict__ PKq, const uint32_t* __restrict__ PQ,
    const float* __restrict__ e_last,
    const float* __restrict__ Va, const float* __restrict__ bv,
    const float* __restrict__ b_ih, const float* __restrict__ b_hh,
    const float* __restrict__ ba, const float* __restrict__ bo,
    const float* __restrict__ Wo,
    float* __restrict__ dout, float* __restrict__ hT_out, float* __restrict__ ca)
{
  __shared__ __align__(16) uint8_t  ukl[65536];   // fp8 UK, this round's batch
  __shared__ __align__(16) uint32_t epl[16384];   // fp8 EP (dwords)
  __shared__ __align__(16) float    scr[16][ND];  // union: qpart/spart(4) | cpart(16) | gpart(12)
  __shared__ float    hf[ND];
  __shared__ float    xin[4];
  __shared__ uint32_t xb[260];                    // bf16 pairs: [0..129]=ctx+x, [130..257]=h, pad
  __shared__ __align__(16) float qL[ND];
  __shared__ __align__(16) float va2[ND];         // 2*Va
  __shared__ float    WoL[3*ND];
  __shared__ __align__(16) float wl[NS];          // softmax weights (f32)
  __shared__ float    red[8];

  const int t    = threadIdx.x;
  const int d    = t & 255;
  const int q4   = t >> 8;
  const int lane = t & 63;
  const int w    = t >> 6;
  const int b0   = blockIdx.x * 2;

  // ---- one-time init ----
  if (q4 == 0){
    va2[d] = 2.0f*Va[d];
    WoL[d] = Wo[d]; WoL[256+d] = Wo[256+d]; WoL[512+d] = Wo[512+d];
  }
  const float bias_r  = b_ih[d]     + b_hh[d];
  const float bias_z  = b_ih[256+d] + b_hh[256+d];
  const float bias_ni = b_ih[512+d];
  const float bias_nh = b_hh[512+d];
  const float ba_d = ba[d];
  const float bv0  = bv[0];
  const float bo0 = bo[0], bo1 = bo[1], bo2 = bo[2];
  __syncthreads();
  float sumVaQ = 0.f;      // sum of Va over e in [q4*64, q4*64+64)
  {
    #pragma unroll 8
    for (int e = q4*64; e < q4*64+64; ++e) sumVaQ += va2[e];
    sumVaQ *= 0.5f;
  }

  #pragma unroll 1
  for (int r=0; r<2; ++r){
    const int b = b0 + r;

    // ---- per-round init: LDS data load + state reset ----
    {
      const uint4* srcU = (const uint4*)(UKQ + (size_t)b*65536);
      uint4* dstU = (uint4*)ukl;
      #pragma unroll
      for (int i=0;i<4;i++) dstU[t + i*1024] = srcU[t + i*1024];
      const uint4* srcE = (const uint4*)(EPQ + (size_t)b*16384);
      uint4* dstE = (uint4*)epl;
      #pragma unroll
      for (int i=0;i<4;i++) dstE[t + i*1024] = srcE[t + i*1024];
    }
    if (q4 == 0){
      hf[d] = e_last[(size_t)b*ND + d];
      if (d < 4) xin[d] = 0.f;
    }
    __syncthreads();
    if (t < 128) xb[130+t] = pack2(hf[2*t], hf[2*t+1]);
    if (t == 128){ xb[128]=0u; xb[129]=0u; xb[258]=0u; xb[259]=0u; }
    __syncthreads();

    float* ca_b = ca   + (size_t)b*(NT*NS);
    float* do_b = dout + (size_t)b*(NT*NO);

    #pragma unroll 1
    for (int step=0; step<NT; ++step){
      // ---- Q: q = h @ Wa^T + ba ; quarter q4 of k2 (32 each) ----
      {
        float aq = 0.f;
        const uint32_t* pq = PQ + (size_t)(q4*32)*256 + d;
        const uint32_t* xh = &xb[130 + q4*32];
        #pragma unroll 1
        for (int kk=0; kk<32; kk+=8){
          uint32_t wv[8], xv[8];
          #pragma unroll
          for (int j=0;j<8;j++){ wv[j] = pq[(kk+j)*256]; xv[j] = xh[kk+j]; }
          #pragma unroll
          for (int j=0;j<8;j++) aq = dot2bf(wv[j], xv[j], aq);
        }
        scr[q4][d] = aq;
      }
      __syncthreads();
      if (q4 == 0)
        qL[d] = ((scr[0][d]+scr[1][d]) + (scr[2][d]+scr[3][d]) + ba_d) * C2;
      __syncthreads();

      // ---- S: scores (s=d, e-quarter q4) from LDS fp8 ; folded tanh ----
      {
        float acc = 0.f;
        #pragma unroll
        for (int j=0;j<4;j++){
          uint4 u = *(const uint4*)(ukl + (size_t)(q4*4+j)*4096 + d*16);
          const float* qb = &qL[q4*64 + j*16];
          const float* vb = &va2[q4*64 + j*16];
          acc = s_dword(u.x, *(const float4*)&qb[0],  *(const float4*)&vb[0],  acc);
          acc = s_dword(u.y, *(const float4*)&qb[4],  *(const float4*)&vb[4],  acc);
          acc = s_dword(u.z, *(const float4*)&qb[8],  *(const float4*)&vb[8],  acc);
          acc = s_dword(u.w, *(const float4*)&qb[12], *(const float4*)&vb[12], acc);
        }
        scr[q4][d] = sumVaQ - acc;   // qpart dead; reuse rows 0-3
      }
      __syncthreads();

      // ---- softmax (no max-subtract; |score| <= sum|Va|+|bv| is small) ----
      float p_reg = 0.f;
      if (q4 == 0){
        float sc = (scr[0][d]+scr[1][d]) + (scr[2][d]+scr[3][d]) + bv0;
        p_reg = exp2_fast(sc * LOG2E);
        float ssum = p_reg;
        #pragma unroll
        for (int o=32;o;o>>=1) ssum += __shfl_xor(ssum, o);
        if (lane==0) red[w] = ssum;      // waves 0-3
      }
      __syncthreads();
      if (q4 == 0){
        float ssum = (red[0]+red[1]) + (red[2]+red[3]);
        float wgt = p_reg * rcp_fast(ssum);
        __builtin_nontemporal_store(wgt, &ca_b[(size_t)step*NS + d]);
        wl[d] = wgt;
      }
      __syncthreads();

      // ---- C: ctx from LDS fp8 ; wave w -> s4 in [w*4, w*4+4) ----
      {
        float c0=0,c1=0,c2=0,c3=0;
        #pragma unroll
        for (int i=0;i<4;i++){
          int s4 = w*4 + i;
          uint4 ev = *(const uint4*)(epl + (size_t)s4*256 + lane*4);
          float4 w4 = *(const float4*)&wl[s4*4];
          c0 = c_dword(ev.x, w4, c0);
          c1 = c_dword(ev.y, w4, c1);
          c2 = c_dword(ev.z, w4, c2);
          c3 = c_dword(ev.w, w4, c3);
        }
        *(float4*)&scr[w][lane*4] = make_float4(c0,c1,c2,c3);
      }
      __syncthreads();
      if (q4 == 0){
        float cx = 0.f;
        #pragma unroll
        for (int i=0;i<16;i++) cx += scr[i][d];
        float other = __shfl_xor(cx, 1);
        if (!(d&1)) xb[d>>1] = pack2(cx, other);
        if (d==128) xb[128] = pack2(xin[0], xin[1]);
        if (d==129) xb[129] = pack2(xin[2], 0.f);
      }
      __syncthreads();

      // ---- G: gates ; quarter q4 of k2 (65 each: 0,1=x-part; 2,3=h-part) ----
      {
        float ar=0.f, az=0.f, an=0.f;
        const int k0 = q4*65;
        const uint32_t* pk = PKq + (size_t)k0*768 + d;
        #pragma unroll 1
        for (int g=0; g<64; g+=8){
          uint32_t wr[8], wz[8], wn[8], xv[8];
          #pragma unroll
          for (int j=0;j<8;j++){
            const uint32_t* p = pk + (size_t)(g+j)*768;
            wr[j]=p[0]; wz[j]=p[256]; wn[j]=p[512];
            xv[j]=xb[k0+g+j];
          }
          #pragma unroll
          for (int j=0;j<8;j++){
            ar=dot2bf(wr[j],xv[j],ar); az=dot2bf(wz[j],xv[j],az); an=dot2bf(wn[j],xv[j],an);
          }
        }
        { // 65th k2
          const uint32_t* p = pk + (size_t)64*768;
          uint32_t xa = xb[k0+64];
          ar=dot2bf(p[0],xa,ar); az=dot2bf(p[256],xa,az); an=dot2bf(p[512],xa,an);
        }
        scr[q4*3+0][d]=ar; scr[q4*3+1][d]=az; scr[q4*3+2][d]=an;
      }
      __syncthreads();
      if (q4 == 0){
        float ar  = (scr[0][d]+scr[3][d]) + (scr[6][d]+scr[9][d]) + bias_r;
        float az  = (scr[1][d]+scr[4][d]) + (scr[7][d]+scr[10][d]) + bias_z;
        float ani =  scr[2][d]+scr[5][d]  + bias_ni;   // x-part (k2<130)
        float anh =  scr[8][d]+scr[11][d] + bias_nh;   // h-part
        float rg = sigm_f(ar);
        float zg = sigm_f(az);
        float ng = tanh_f(ani + rg*anh);
        float hnew = (1.f-zg)*ng + zg*hf[d];
        hf[d] = hnew;
        float other = __shfl_xor(hnew, 1);
        if (!(d&1)) xb[130 + (d>>1)] = pack2(hnew, other);
      }
      __syncthreads();

      // ---- out projection: wave 0 ----
      if (w == 0){
        float p0=0,p1=0,p2=0;
        #pragma unroll
        for (int i=0;i<4;i++){
          float hv = hf[i*64 + lane];
          p0 = fmaf(hv, WoL[      i*64+lane], p0);
          p1 = fmaf(hv, WoL[256 + i*64+lane], p1);
          p2 = fmaf(hv, WoL[512 + i*64+lane], p2);
        }
        #pragma unroll
        for (int o=32;o;o>>=1){
          p0+=__shfl_xor(p0,o); p1+=__shfl_xor(p1,o); p2+=__shfl_xor(p2,o);
        }
        if (lane==0){
          float o0=p0+bo0, o1=p1+bo1, o2=p2+bo2;
          __builtin_nontemporal_store(o0, &do_b[(size_t)step*NO+0]);
          __builtin_nontemporal_store(o1, &do_b[(size_t)step*NO+1]);
          __builtin_nontemporal_store(o2, &do_b[(size_t)step*NO+2]);
          xin[0]=o0; xin[1]=o1; xin[2]=o2;
        }
      }
      // next step's barriers order xin/hf consumers
    }

    __syncthreads();
    if (q4 == 0) hT_out[(size_t)b*ND + d] = hf[d];
    __syncthreads();   // before next round overwrites LDS
  }
}

// ---------------- host launch ----------------

extern "C" void kernel_launch(void* const* d_in, const int* in_sizes, int n_in,
                              void* d_out, int out_size, void* d_ws, size_t ws_size,
                              hipStream_t stream) {
  const float* e_all  = (const float*)d_in[0];
  const float* e_last = (const float*)d_in[1];
  const float* Wa     = (const float*)d_in[2];
  const float* ba     = (const float*)d_in[3];
  const float* Ua     = (const float*)d_in[4];
  const float* bu     = (const float*)d_in[5];
  const float* Va     = (const float*)d_in[6];
  const float* bv     = (const float*)d_in[7];
  const float* W_ih   = (const float*)d_in[8];
  const float* b_ih   = (const float*)d_in[9];
  const float* W_hh   = (const float*)d_in[10];
  const float* b_hh   = (const float*)d_in[11];
  const float* Wo     = (const float*)d_in[12];
  const float* bo     = (const float*)d_in[13];

  // workspace layout (~68.3 MB)
  char* ws = (char*)d_ws;
  uint8_t*  UKQ = (uint8_t*) (ws + 0ull);            // fp8 [B][16][S][16]    33554432 B
  uint32_t* EPQ = (uint32_t*)(ws + 33554432ull);     // u32 [B][64][256]      33554432 B
  uint32_t* PKq = (uint32_t*)(ws + 67108864ull);     // u32 [260][3][256]       798720 B
  uint32_t* PQ  = (uint32_t*)(ws + 67907584ull);     // u32 [128][256]          131072 B
  float*    UaT = (float*)   (ws + 68038656ull);     // f32 [256][256]          262144 B

  float* dout = (float*)d_out;                       // [B][T][3]
  float* hT   = dout + (size_t)NB*NT*NO;             // [B][D]
  float* ca   = hT   + (size_t)NB*ND;                // [B][T*S]

  // prep
  k_transpose<<<(ND*ND+255)/256,256,0,stream>>>(Ua, UaT, ND, ND);
  k_uk<<<NB*NS/16,256,0,stream>>>(e_all, UaT, bu, UKQ);
  k_epq<<<(NB*64*256+255)/256,256,0,stream>>>(e_all, EPQ);
  k_pkq<<<(260*3*256+255)/256,256,0,stream>>>(W_ih, W_hh, PKq);
  k_pack_q<<<(128*256+255)/256,256,0,stream>>>(Wa, PQ);

  // persistent decode: 256 blocks x 1024 threads; 2 sequential rounds/block
  k_decode<<<NB/2,1024,0,stream>>>(UKQ, EPQ, PKq, PQ, e_last, Va, bv,
                                   b_ih, b_hh, ba, bo, Wo, dout, hT, ca);
}